// Round 1
// baseline (117.784 us; speedup 1.0000x reference)
//
#include <hip/hip_runtime.h>
#include <math.h>

#define H 2048
#define V 50257

__device__ __forceinline__ float wave_reduce_sum(float v) {
#pragma unroll
    for (int off = 32; off > 0; off >>= 1)
        v += __shfl_down(v, off, 64);
    return v;
}

__device__ __forceinline__ float wave_reduce_max(float v) {
#pragma unroll
    for (int off = 32; off > 0; off >>= 1)
        v = fmaxf(v, __shfl_down(v, off, 64));
    return v;
}

// x = relu(embedding[idx])
__global__ void k_embed(const int* __restrict__ idx_p,
                        const float* __restrict__ emb,
                        float* __restrict__ x) {
    int i = blockIdx.x * blockDim.x + threadIdx.x;
    if (i < H) {
        long idx = (long)idx_p[0];
        float v = emb[idx * (long)H + i];
        x[i] = v > 0.f ? v : 0.f;
    }
}

// One block per hidden element j. 6 waves: waves 0-2 dot w_ih rows (j, H+j, 2H+j)
// with x; waves 3-5 dot w_hh rows with h. Lane/thread 0 applies GRU gate math.
__global__ __launch_bounds__(384) void k_gru(
    const float* __restrict__ w_ih, const float* __restrict__ w_hh,
    const float* __restrict__ b_ih, const float* __restrict__ b_hh,
    const float* __restrict__ x, const float* __restrict__ hid,
    float* __restrict__ hnew_ws, float* __restrict__ hnew_out) {
    __shared__ float xs[H];
    __shared__ float hs[H];
    __shared__ float partial[6];
    int tid = threadIdx.x;
    for (int i = tid; i < H / 4; i += 384) {
        ((float4*)xs)[i] = ((const float4*)x)[i];
        ((float4*)hs)[i] = ((const float4*)hid)[i];
    }
    __syncthreads();

    int wid = tid >> 6, lane = tid & 63;
    int j = blockIdx.x;
    int gate = wid % 3;  // 0:r 1:z 2:n
    const float* W = (wid < 3) ? w_ih : w_hh;
    const float* vec = (wid < 3) ? xs : hs;
    const float* row = W + (size_t)(gate * H + j) * (size_t)H;

    float acc = 0.f;
#pragma unroll
    for (int it = 0; it < 8; ++it) {
        float4 w4 = ((const float4*)row)[it * 64 + lane];
        float4 v4 = ((const float4*)vec)[it * 64 + lane];
        acc += w4.x * v4.x + w4.y * v4.y + w4.z * v4.z + w4.w * v4.w;
    }
    acc = wave_reduce_sum(acc);
    if (lane == 0) partial[wid] = acc;
    __syncthreads();

    if (tid == 0) {
        float i_r = partial[0] + b_ih[j];
        float i_z = partial[1] + b_ih[H + j];
        float i_n = partial[2] + b_ih[2 * H + j];
        float h_r = partial[3] + b_hh[j];
        float h_z = partial[4] + b_hh[H + j];
        float h_n = partial[5] + b_hh[2 * H + j];
        float r = 1.f / (1.f + expf(-(i_r + h_r)));
        float z = 1.f / (1.f + expf(-(i_z + h_z)));
        float n = tanhf(i_n + r * h_n);
        float hv = (1.f - z) * n + z * hs[j];
        hnew_ws[j] = hv;
        hnew_out[j] = hv;
    }
}

// One wave per vocab row; h_new staged in LDS; coalesced float4 weight reads.
__global__ __launch_bounds__(256) void k_logits(
    const float* __restrict__ out_w, const float* __restrict__ out_b,
    const float* __restrict__ hnew, float* __restrict__ logits) {
    __shared__ float hs[H];
    int tid = threadIdx.x;
    for (int i = tid; i < H / 4; i += 256)
        ((float4*)hs)[i] = ((const float4*)hnew)[i];
    __syncthreads();

    int wid = tid >> 6, lane = tid & 63;
    int r = blockIdx.x * 4 + wid;
    if (r >= V) return;
    const float* row = out_w + (size_t)r * (size_t)H;

    float acc = 0.f;
#pragma unroll
    for (int it = 0; it < 8; ++it) {
        float4 w4 = ((const float4*)row)[it * 64 + lane];
        float4 v4 = ((const float4*)hs)[it * 64 + lane];
        acc += w4.x * v4.x + w4.y * v4.y + w4.z * v4.z + w4.w * v4.w;
    }
    acc = wave_reduce_sum(acc);
    if (lane == 0) logits[r] = acc + out_b[r];
}

// Single block: global max then log-sum-exp over logits (L2-resident).
__global__ __launch_bounds__(1024) void k_lse(const float* __restrict__ logits,
                                              float* __restrict__ stats) {
    __shared__ float red[16];
    __shared__ float m_s;
    int tid = threadIdx.x;

    float m = -INFINITY;
    for (int i = tid; i < V; i += 1024) m = fmaxf(m, logits[i]);
    m = wave_reduce_max(m);
    if ((tid & 63) == 0) red[tid >> 6] = m;
    __syncthreads();
    if (tid < 16) {
        m = red[tid];
#pragma unroll
        for (int off = 8; off > 0; off >>= 1)
            m = fmaxf(m, __shfl_down(m, off, 64));
        if (tid == 0) m_s = m;
    }
    __syncthreads();
    float gm = m_s;

    float s = 0.f;
    for (int i = tid; i < V; i += 1024) s += expf(logits[i] - gm);
    s = wave_reduce_sum(s);
    __syncthreads();  // ensure all reads of red (max phase) done before overwrite
    if ((tid & 63) == 0) red[tid >> 6] = s;
    __syncthreads();
    if (tid == 0) {
        float tot = 0.f;
#pragma unroll
        for (int w = 0; w < 16; ++w) tot += red[w];
        stats[0] = gm;
        stats[1] = logf(tot);
    }
}

__global__ void k_finalize(const float* __restrict__ logits,
                           const float* __restrict__ stats,
                           float* __restrict__ out) {
    int i = blockIdx.x * blockDim.x + threadIdx.x;
    if (i < V) out[i] = logits[i] - stats[0] - stats[1];
}

extern "C" void kernel_launch(void* const* d_in, const int* in_sizes, int n_in,
                              void* d_out, int out_size, void* d_ws, size_t ws_size,
                              hipStream_t stream) {
    const int*   idx    = (const int*)d_in[0];
    const float* hidden = (const float*)d_in[1];
    const float* emb    = (const float*)d_in[2];
    const float* w_ih   = (const float*)d_in[3];
    const float* w_hh   = (const float*)d_in[4];
    const float* b_ih   = (const float*)d_in[5];
    const float* b_hh   = (const float*)d_in[6];
    const float* out_w  = (const float*)d_in[7];
    const float* out_b  = (const float*)d_in[8];

    float* out = (float*)d_out;            // [V logp][H hnew]
    float* ws  = (float*)d_ws;
    float* x      = ws;                    // H floats
    float* hnew   = ws + H;                // H floats
    float* logits = ws + 2 * H;            // V floats
    float* stats  = ws + 2 * H + ((V + 63) & ~63);  // 2 floats

    k_embed<<<(H + 255) / 256, 256, 0, stream>>>(idx, emb, x);
    k_gru<<<H, 384, 0, stream>>>(w_ih, w_hh, b_ih, b_hh, x, hidden, hnew, out + V);
    k_logits<<<(V + 3) / 4, 256, 0, stream>>>(out_w, out_b, hnew, logits);
    k_lse<<<1, 1024, 0, stream>>>(logits, stats);
    k_finalize<<<(V + 255) / 256, 256, 0, stream>>>(logits, stats, out);
}

// Round 2
// 100.009 us; speedup vs baseline: 1.1777x; 1.1777x over previous
//
#include <hip/hip_runtime.h>
#include <math.h>

#define H 2048
#define V 50257

#define LOGITS_BLOCKS 2048
#define LOGITS_WAVES (LOGITS_BLOCKS * 4)   // 256 threads = 4 waves per block
#define FIN_BLOCKS 52

__device__ __forceinline__ float wave_reduce_sum(float v) {
#pragma unroll
    for (int off = 32; off > 0; off >>= 1)
        v += __shfl_down(v, off, 64);
    return v;
}

// ---------------------------------------------------------------------------
// GRU step, embed fused. 1024 blocks, each handles hidden elements j and j+1024.
// 6 waves per block: waves 0-2 dot w_ih gate rows with x=relu(emb[idx]);
// waves 3-5 dot w_hh gate rows with h. Each wave does 2 rows (16 loads in flight).
// ---------------------------------------------------------------------------
__global__ __launch_bounds__(384) void k_gru(
    const int* __restrict__ idx_p,
    const float* __restrict__ emb,
    const float* __restrict__ hid,
    const float* __restrict__ w_ih, const float* __restrict__ w_hh,
    const float* __restrict__ b_ih, const float* __restrict__ b_hh,
    float* __restrict__ hnew_ws, float* __restrict__ hnew_out) {
    __shared__ float xs[H];
    __shared__ float hs[H];
    __shared__ float partial[6][2];
    int tid = threadIdx.x;

    long idx = (long)idx_p[0];
    const float4* embrow = (const float4*)(emb + idx * (long)H);
    for (int i = tid; i < H / 4; i += 384) {
        float4 e = embrow[i];
        e.x = fmaxf(e.x, 0.f); e.y = fmaxf(e.y, 0.f);
        e.z = fmaxf(e.z, 0.f); e.w = fmaxf(e.w, 0.f);
        ((float4*)xs)[i] = e;
        ((float4*)hs)[i] = ((const float4*)hid)[i];
    }
    __syncthreads();

    int wid = tid >> 6, lane = tid & 63;
    int gate = wid % 3;
    const float* W   = (wid < 3) ? w_ih : w_hh;
    const float* vec = (wid < 3) ? xs : hs;
    int j0 = blockIdx.x;
    int j1 = blockIdx.x + 1024;
    const float4* r0 = (const float4*)(W + ((size_t)gate * H + j0) * (size_t)H);
    const float4* r1 = (const float4*)(W + ((size_t)gate * H + j1) * (size_t)H);

    float4 vreg[8];
#pragma unroll
    for (int it = 0; it < 8; ++it)
        vreg[it] = ((const float4*)vec)[it * 64 + lane];

    float a0 = 0.f, a1 = 0.f;
#pragma unroll
    for (int it = 0; it < 8; ++it) {
        float4 wa = r0[it * 64 + lane];
        float4 wb = r1[it * 64 + lane];
        a0 += wa.x * vreg[it].x + wa.y * vreg[it].y + wa.z * vreg[it].z + wa.w * vreg[it].w;
        a1 += wb.x * vreg[it].x + wb.y * vreg[it].y + wb.z * vreg[it].z + wb.w * vreg[it].w;
    }
    a0 = wave_reduce_sum(a0);
    a1 = wave_reduce_sum(a1);
    if (lane == 0) { partial[wid][0] = a0; partial[wid][1] = a1; }
    __syncthreads();

    if (tid < 2) {
        int j = (tid == 0) ? j0 : j1;
        float i_r = partial[0][tid] + b_ih[j];
        float i_z = partial[1][tid] + b_ih[H + j];
        float i_n = partial[2][tid] + b_ih[2 * H + j];
        float h_r = partial[3][tid] + b_hh[j];
        float h_z = partial[4][tid] + b_hh[H + j];
        float h_n = partial[5][tid] + b_hh[2 * H + j];
        float r = 1.f / (1.f + expf(-(i_r + h_r)));
        float z = 1.f / (1.f + expf(-(i_z + h_z)));
        float n = tanhf(i_n + r * h_n);
        float hv = (1.f - z) * n + z * hs[j];
        hnew_ws[j] = hv;
        hnew_out[j] = hv;
    }
}

// ---------------------------------------------------------------------------
// Vocab projection, persistent grid-stride waves. h_new lives in registers.
// Each block also emits an online (max, sum-exp) partial for log-softmax.
// ---------------------------------------------------------------------------
__global__ __launch_bounds__(256) void k_logits(
    const float* __restrict__ out_w, const float* __restrict__ out_b,
    const float* __restrict__ hnew,
    float* __restrict__ logits, float2* __restrict__ partials) {
    __shared__ float hs[H];
    __shared__ float pm[4], ps[4];
    int tid = threadIdx.x;
    for (int i = tid; i < H / 4; i += 256)
        ((float4*)hs)[i] = ((const float4*)hnew)[i];
    __syncthreads();

    int wid = tid >> 6, lane = tid & 63;
    float4 vreg[8];
#pragma unroll
    for (int it = 0; it < 8; ++it)
        vreg[it] = ((const float4*)hs)[it * 64 + lane];

    float m = -INFINITY, s = 0.f;
    for (int r = blockIdx.x * 4 + wid; r < V; r += LOGITS_WAVES) {
        const float4* row = (const float4*)(out_w + (size_t)r * (size_t)H);
        float acc = 0.f;
#pragma unroll
        for (int it = 0; it < 8; ++it) {
            float4 w4 = row[it * 64 + lane];
            acc += w4.x * vreg[it].x + w4.y * vreg[it].y + w4.z * vreg[it].z + w4.w * vreg[it].w;
        }
        acc = wave_reduce_sum(acc);
        if (lane == 0) {
            float l = acc + out_b[r];
            logits[r] = l;
            float M = fmaxf(m, l);
            s = s * __expf(m - M) + __expf(l - M);
            m = M;
        }
    }
    if (lane == 0) { pm[wid] = m; ps[wid] = s; }
    __syncthreads();
    if (tid == 0) {
        float M = fmaxf(fmaxf(pm[0], pm[1]), fmaxf(pm[2], pm[3]));
        float S = ps[0] * __expf(pm[0] - M) + ps[1] * __expf(pm[1] - M) +
                  ps[2] * __expf(pm[2] - M) + ps[3] * __expf(pm[3] - M);
        partials[blockIdx.x] = make_float2(M, S);
    }
}

// ---------------------------------------------------------------------------
// Merge the 2048 block partials (every block redundantly; 16 KB, L2-hot),
// then write logp = logits - (m + log(s)) with float4 stores.
// ---------------------------------------------------------------------------
__global__ __launch_bounds__(256) void k_finalize(
    const float* __restrict__ logits, const float2* __restrict__ partials,
    float* __restrict__ out) {
    __shared__ float pm[4], ps[4];
    __shared__ float cs;
    int tid = threadIdx.x;

    float m = -INFINITY, s = 0.f;
    for (int i = tid; i < LOGITS_BLOCKS; i += 256) {
        float2 p = partials[i];
        float M = fmaxf(m, p.x);
        s = s * __expf(m - M) + p.y * __expf(p.x - M);
        m = M;
    }
#pragma unroll
    for (int off = 32; off > 0; off >>= 1) {
        float om = __shfl_down(m, off, 64);
        float os = __shfl_down(s, off, 64);
        float M = fmaxf(m, om);
        s = s * __expf(m - M) + os * __expf(om - M);
        m = M;
    }
    int wid = tid >> 6, lane = tid & 63;
    if (lane == 0) { pm[wid] = m; ps[wid] = s; }
    __syncthreads();
    if (tid == 0) {
        float M = fmaxf(fmaxf(pm[0], pm[1]), fmaxf(pm[2], pm[3]));
        float S = ps[0] * __expf(pm[0] - M) + ps[1] * __expf(pm[1] - M) +
                  ps[2] * __expf(pm[2] - M) + ps[3] * __expf(pm[3] - M);
        cs = M + logf(S);
    }
    __syncthreads();
    float C = cs;

    int gid = blockIdx.x * 256 + tid;
    const int nf = V / 4;  // 12564 full float4s
    for (int i = gid; i < nf; i += FIN_BLOCKS * 256) {
        float4 l4 = ((const float4*)logits)[i];
        l4.x -= C; l4.y -= C; l4.z -= C; l4.w -= C;
        ((float4*)out)[i] = l4;
    }
    if (gid == 0) {
        for (int i = nf * 4; i < V; ++i) out[i] = logits[i] - C;
    }
}

extern "C" void kernel_launch(void* const* d_in, const int* in_sizes, int n_in,
                              void* d_out, int out_size, void* d_ws, size_t ws_size,
                              hipStream_t stream) {
    const int*   idx    = (const int*)d_in[0];
    const float* hidden = (const float*)d_in[1];
    const float* emb    = (const float*)d_in[2];
    const float* w_ih   = (const float*)d_in[3];
    const float* w_hh   = (const float*)d_in[4];
    const float* b_ih   = (const float*)d_in[5];
    const float* b_hh   = (const float*)d_in[6];
    const float* out_w  = (const float*)d_in[7];
    const float* out_b  = (const float*)d_in[8];

    float* out = (float*)d_out;                 // [V logp][H hnew]
    float* ws  = (float*)d_ws;
    float*  hnew     = ws;                      // H floats
    float*  logits   = ws + H;                  // V floats
    float2* partials = (float2*)(ws + H + ((V + 1) & ~1));  // LOGITS_BLOCKS float2

    k_gru<<<1024, 384, 0, stream>>>(idx, emb, hidden, w_ih, w_hh, b_ih, b_hh,
                                    hnew, out + V);
    k_logits<<<LOGITS_BLOCKS, 256, 0, stream>>>(out_w, out_b, hnew, logits, partials);
    k_finalize<<<FIN_BLOCKS, 256, 0, stream>>>(logits, partials, out);
}